// Round 1
// baseline (509.039 us; speedup 1.0000x reference)
//
#include <hip/hip_runtime.h>
#include <hip/hip_bf16.h>

#define N_NODES 10000
#define N_EDGES 160000
#define DD 1024
#define KCAT 2048
#define MPAD 10240
#define MTILES 79   // ceil(10000/128), covers rows 0..10111

typedef __attribute__((ext_vector_type(8))) __bf16 bf16x8;
typedef __attribute__((ext_vector_type(4))) __bf16 bf16x4;
typedef __attribute__((ext_vector_type(4))) float f32x4;

// ---------------- async global->LDS (16B, linear dest) ----------------
__device__ inline void gload_lds16(const void* g, void* l) {
  __builtin_amdgcn_global_load_lds((const __attribute__((address_space(1))) void*)g,
                                   (__attribute__((address_space(3))) void*)l, 16, 0, 0);
}

// ---------------- CSR build ----------------
__global__ __launch_bounds__(256) void k_hist(const int* __restrict__ dst,
                                              int* __restrict__ deg) {
  int e = blockIdx.x * 256 + threadIdx.x;
  if (e < N_EDGES) atomicAdd(&deg[dst[e]], 1);
}

__global__ __launch_bounds__(1024) void k_scan(const int* __restrict__ deg,
                                               int* __restrict__ off) {
  __shared__ int sh[1024];
  __shared__ int carry_s;
  int t = threadIdx.x;
  if (t == 0) carry_s = 0;
  for (int base = 0; base < N_NODES; base += 1024) {
    int v = (base + t < N_NODES) ? deg[base + t] : 0;
    __syncthreads();
    sh[t] = v;
    __syncthreads();
    int c0 = carry_s;
    for (int s = 1; s < 1024; s <<= 1) {
      int x = (t >= s) ? sh[t - s] : 0;
      __syncthreads();
      sh[t] += x;
      __syncthreads();
    }
    if (base + t < N_NODES) off[base + t] = c0 + sh[t] - v;  // exclusive
    int tot = sh[1023];
    __syncthreads();
    if (t == 0) carry_s = c0 + tot;
  }
  __syncthreads();
  if (t == 0) off[N_NODES] = carry_s;
}

__global__ __launch_bounds__(256) void k_fill(const int* __restrict__ src,
                                              const int* __restrict__ dst,
                                              const int* __restrict__ off,
                                              int* __restrict__ cursor,
                                              int* __restrict__ eidx) {
  int e = blockIdx.x * 256 + threadIdx.x;
  if (e < N_EDGES) {
    int d = dst[e];
    int pos = atomicAdd(&cursor[d], 1);
    eidx[off[d] + pos] = src[e];
  }
}

// ---------------- embedding gather -> bf16 (left half of xcat) ----------------
__global__ __launch_bounds__(256) void k_embed(const int* __restrict__ node,
                                               const float* __restrict__ emb,
                                               __bf16* __restrict__ xcat) {
  int i = blockIdx.x;      // 10000
  int t = threadIdx.x;     // 256, 4 floats each
  float4 v = ((const float4*)(emb + (size_t)node[i] * DD))[t];
  bf16x4 o;
  o[0] = (__bf16)v.x; o[1] = (__bf16)v.y; o[2] = (__bf16)v.z; o[3] = (__bf16)v.w;
  *(bf16x4*)(xcat + (size_t)i * KCAT + t * 4) = o;
}

// ---------------- weights: [Wself;Wneigh] -> W^T bf16 [1024][2048] ----------------
__global__ __launch_bounds__(256) void k_wconv(const float* __restrict__ Ws,
                                               const float* __restrict__ Wn,
                                               __bf16* __restrict__ Wt) {
  __shared__ float tile[32][33];
  int k0 = blockIdx.x * 32;  // 0..2047
  int c0 = blockIdx.y * 32;  // 0..1023
  for (int i = threadIdx.y; i < 32; i += 8) {
    int k = k0 + i, c = c0 + threadIdx.x;
    float v = (k < DD) ? Ws[(size_t)k * DD + c] : Wn[(size_t)(k - DD) * DD + c];
    tile[i][threadIdx.x] = v;
  }
  __syncthreads();
  for (int i = threadIdx.y; i < 32; i += 8) {
    int c = c0 + i, k = k0 + threadIdx.x;
    Wt[(size_t)c * KCAT + k] = (__bf16)tile[threadIdx.x][i];
  }
}

// ---------------- mean aggregation: right half of buf <- mean of left-half rows ----------------
__global__ __launch_bounds__(256) void k_agg(__bf16* __restrict__ buf,
                                             const int* __restrict__ off,
                                             const int* __restrict__ eidx) {
  int d = blockIdx.x;      // dst node
  int t = threadIdx.x;     // 4 cols each
  int s = off[d], e = off[d + 1];
  float a0 = 0.f, a1 = 0.f, a2 = 0.f, a3 = 0.f;
  for (int i = s; i < e; ++i) {
    int r = eidx[i];
    bf16x4 v = *(const bf16x4*)(buf + (size_t)r * KCAT + t * 4);
    a0 += (float)v[0]; a1 += (float)v[1]; a2 += (float)v[2]; a3 += (float)v[3];
  }
  float inv = 1.0f / fmaxf((float)(e - s), 1.0f);
  bf16x4 o;
  o[0] = (__bf16)(a0 * inv); o[1] = (__bf16)(a1 * inv);
  o[2] = (__bf16)(a2 * inv); o[3] = (__bf16)(a3 * inv);
  *(bf16x4*)(buf + (size_t)d * KCAT + DD + t * 4) = o;
}

// ---------------- GEMM: C[M,1024] = A[M,2048] @ Wt^T + bias ----------------
// A row-major [MPAD][2048] bf16; Bt row-major [1024][2048] bf16 (= W^T).
// 128x128 tile, BK=64, 4 waves (2x2), each wave 64x64 = 4x4 frags of 16x16x32.
// LDS: linear-write via global_load_lds with pre-swizzled SOURCE; swizzled ds_read
// (byte ^= (row&7)<<4) -> conflict-free b128 reads (guide rule #21 / G4).
// MODE 0: f32 out + bias (layer 2). MODE 1: bf16 out + bias + relu (layer 1).
template <int MODE>
__global__ __launch_bounds__(256) void k_gemm(const __bf16* __restrict__ A,
                                              const __bf16* __restrict__ Bt,
                                              const float* __restrict__ bias,
                                              float* __restrict__ Cf,
                                              __bf16* __restrict__ Cb,
                                              int Mreal) {
  __shared__ uint4 smemq[2048];         // 32 KB: A-tile 16KB | B-tile 16KB
  char* As = (char*)smemq;
  char* Bs = As + 16384;
  const int tid  = threadIdx.x;
  const int lane = tid & 63;
  const int w    = tid >> 6;            // wave 0..3
  const int wr   = w >> 1, wc = w & 1;  // 2x2 wave grid
  const int m0   = blockIdx.x * 128;
  const int n0   = blockIdx.y * 128;

  f32x4 acc[4][4];
#pragma unroll
  for (int m = 0; m < 4; ++m)
#pragma unroll
    for (int n = 0; n < 4; ++n) acc[m][n] = f32x4{0.f, 0.f, 0.f, 0.f};

  // staging source coords: granule G = chunk*64+lane, E = G ^ ((G>>3)&7)
  int sr[4], sk[4];
#pragma unroll
  for (int i = 0; i < 4; ++i) {
    int G = (4 * w + i) * 64 + lane;
    int E = G ^ ((G >> 3) & 7);
    sr[i] = E >> 3;        // tile row/col 0..127
    sk[i] = (E & 7) * 8;   // k offset within BK
  }

  for (int kt = 0; kt < KCAT; kt += 64) {
    __syncthreads();  // previous tile fully consumed
#pragma unroll
    for (int i = 0; i < 4; ++i) {
      gload_lds16(A + (size_t)(m0 + sr[i]) * KCAT + (kt + sk[i]), As + (4 * w + i) * 1024);
      gload_lds16(Bt + (size_t)(n0 + sr[i]) * KCAT + (kt + sk[i]), Bs + (4 * w + i) * 1024);
    }
    __syncthreads();  // compiler drains vmcnt(0) before barrier -> LDS ready
#pragma unroll
    for (int kk = 0; kk < 64; kk += 32) {
      const int koff = kk + ((lane >> 4) * 8);
      bf16x8 af[4], bfr[4];
#pragma unroll
      for (int m = 0; m < 4; ++m) {
        int r = wr * 64 + m * 16 + (lane & 15);
        int byte = ((r * 64 + koff) * 2) ^ ((r & 7) << 4);
        af[m] = *(const bf16x8*)(As + byte);
      }
#pragma unroll
      for (int n = 0; n < 4; ++n) {
        int c = wc * 64 + n * 16 + (lane & 15);
        int byte = ((c * 64 + koff) * 2) ^ ((c & 7) << 4);
        bfr[n] = *(const bf16x8*)(Bs + byte);
      }
#pragma unroll
      for (int m = 0; m < 4; ++m)
#pragma unroll
        for (int n = 0; n < 4; ++n)
          acc[m][n] = __builtin_amdgcn_mfma_f32_16x16x32_bf16(af[m], bfr[n], acc[m][n], 0, 0, 0);
    }
  }

  // epilogue: C/D layout col=lane&15, row=(lane>>4)*4+j (m89-verified)
  const int rb = m0 + wr * 64;
  const int cb = n0 + wc * 64;
#pragma unroll
  for (int m = 0; m < 4; ++m) {
#pragma unroll
    for (int n = 0; n < 4; ++n) {
      int c = cb + n * 16 + (lane & 15);
      float bv = bias[c];
#pragma unroll
      for (int j = 0; j < 4; ++j) {
        int r = rb + m * 16 + (lane >> 4) * 4 + j;
        if (r < Mreal) {
          float v = acc[m][n][j] + bv;
          if constexpr (MODE == 1) {
            v = fmaxf(v, 0.f);
            Cb[(size_t)r * KCAT + c] = (__bf16)v;   // left half of hcat
          } else {
            Cf[(size_t)r * DD + c] = v;
          }
        }
      }
    }
  }
}

// ---------------- launcher ----------------
extern "C" void kernel_launch(void* const* d_in, const int* in_sizes, int n_in,
                              void* d_out, int out_size, void* d_ws, size_t ws_size,
                              hipStream_t stream) {
  const int*   node = (const int*)d_in[0];
  const int*   srcv = (const int*)d_in[1];
  const int*   dstv = (const int*)d_in[2];
  const float* emb  = (const float*)d_in[3];
  const float* W1s  = (const float*)d_in[4];
  const float* W1n  = (const float*)d_in[5];
  const float* b1   = (const float*)d_in[6];
  const float* W2s  = (const float*)d_in[7];
  const float* W2n  = (const float*)d_in[8];
  const float* b2   = (const float*)d_in[9];
  float* out = (float*)d_out;

  char* ws = (char*)d_ws;
  __bf16* xcat = (__bf16*)ws; ws += (size_t)MPAD * KCAT * 2;   // 41.9 MB  [x | hneigh1]
  __bf16* hcat = (__bf16*)ws; ws += (size_t)MPAD * KCAT * 2;   // 41.9 MB  [h1 | hneigh2]
  __bf16* Wt1  = (__bf16*)ws; ws += (size_t)DD * KCAT * 2;     // 4.2 MB
  __bf16* Wt2  = (__bf16*)ws; ws += (size_t)DD * KCAT * 2;     // 4.2 MB
  int* deg    = (int*)ws; ws += 40960;
  int* cursor = (int*)ws; ws += 40960;
  int* off    = (int*)ws; ws += 40960;
  int* eidx   = (int*)ws; ws += (size_t)N_EDGES * 4;

  hipMemsetAsync(deg, 0, N_NODES * sizeof(int), stream);
  hipMemsetAsync(cursor, 0, N_NODES * sizeof(int), stream);

  // CSR by dst
  k_hist<<<(N_EDGES + 255) / 256, 256, 0, stream>>>(dstv, deg);
  k_scan<<<1, 1024, 0, stream>>>(deg, off);
  k_fill<<<(N_EDGES + 255) / 256, 256, 0, stream>>>(srcv, dstv, off, cursor, eidx);

  // inputs -> bf16
  k_embed<<<N_NODES, 256, 0, stream>>>(node, emb, xcat);
  k_wconv<<<dim3(64, 32), dim3(32, 8), 0, stream>>>(W1s, W1n, Wt1);
  k_wconv<<<dim3(64, 32), dim3(32, 8), 0, stream>>>(W2s, W2n, Wt2);

  // layer 1
  k_agg<<<N_NODES, 256, 0, stream>>>(xcat, off, eidx);
  k_gemm<1><<<dim3(MTILES, 8), 256, 0, stream>>>(xcat, Wt1, b1, nullptr, hcat, N_NODES);

  // layer 2
  k_agg<<<N_NODES, 256, 0, stream>>>(hcat, off, eidx);
  k_gemm<0><<<dim3(MTILES, 8), 256, 0, stream>>>(hcat, Wt2, b2, out, nullptr, N_NODES);
}

// Round 2
// 457.459 us; speedup vs baseline: 1.1128x; 1.1128x over previous
//
#include <hip/hip_runtime.h>
#include <hip/hip_bf16.h>

#define N_NODES 10000
#define N_EDGES 160000
#define DD 1024
#define KCAT 2048
#define MPAD 10240
#define MTILES 79   // ceil(10000/128), covers rows 0..10111
#define NTILES 8
#define NBLK (MTILES * NTILES)   // 632 = 8*79

typedef __attribute__((ext_vector_type(8))) __bf16 bf16x8;
typedef __attribute__((ext_vector_type(4))) __bf16 bf16x4;
typedef __attribute__((ext_vector_type(4))) float f32x4;

// ---------------- async global->LDS (16B, linear dest) ----------------
__device__ inline void gload_lds16(const void* g, void* l) {
  __builtin_amdgcn_global_load_lds((const __attribute__((address_space(1))) void*)g,
                                   (__attribute__((address_space(3))) void*)l, 16, 0, 0);
}

// ---------------- CSR build ----------------
__global__ __launch_bounds__(256) void k_hist(const int* __restrict__ dst,
                                              int* __restrict__ deg) {
  int e = blockIdx.x * 256 + threadIdx.x;
  if (e < N_EDGES) atomicAdd(&deg[dst[e]], 1);
}

// 1024 threads, 10 elems/thread, shfl wave-scan + serial wave-total scan (3 barriers)
__global__ __launch_bounds__(1024) void k_scan(const int* __restrict__ deg,
                                               int* __restrict__ off) {
  int t = threadIdx.x;
  int base_i = t * 10;
  int loc[10];
  int sum = 0;
#pragma unroll
  for (int j = 0; j < 10; ++j) {
    int idx = base_i + j;
    int v = (idx < N_NODES) ? deg[idx] : 0;
    loc[j] = sum;           // exclusive within chunk
    sum += v;
  }
  int lane = t & 63, w = t >> 6;
  int inc = sum;            // inclusive wave scan of chunk totals
#pragma unroll
  for (int d = 1; d < 64; d <<= 1) {
    int y = __shfl_up(inc, d);
    if (lane >= d) inc += y;
  }
  __shared__ int wtot[16];
  __shared__ int wpre[16];
  if (lane == 63) wtot[w] = inc;
  __syncthreads();
  if (t == 0) {
    int c = 0;
    for (int k = 0; k < 16; ++k) { wpre[k] = c; c += wtot[k]; }
    off[N_NODES] = c;       // total edges
  }
  __syncthreads();
  int tbase = wpre[w] + (inc - sum);   // exclusive prefix at this thread's chunk start
#pragma unroll
  for (int j = 0; j < 10; ++j) {
    int idx = base_i + j;
    if (idx < N_NODES) off[idx] = tbase + loc[j];
  }
}

__global__ __launch_bounds__(256) void k_fill(const int* __restrict__ src,
                                              const int* __restrict__ dst,
                                              const int* __restrict__ off,
                                              int* __restrict__ cursor,
                                              int* __restrict__ eidx) {
  int e = blockIdx.x * 256 + threadIdx.x;
  if (e < N_EDGES) {
    int d = dst[e];
    int pos = atomicAdd(&cursor[d], 1);
    eidx[off[d] + pos] = src[e];
  }
}

// ---------------- embedding gather -> bf16 (left half of xcat) ----------------
__global__ __launch_bounds__(256) void k_embed(const int* __restrict__ node,
                                               const float* __restrict__ emb,
                                               __bf16* __restrict__ xcat) {
  int i = blockIdx.x;
  int t = threadIdx.x;
  float4 v = ((const float4*)(emb + (size_t)node[i] * DD))[t];
  bf16x4 o;
  o[0] = (__bf16)v.x; o[1] = (__bf16)v.y; o[2] = (__bf16)v.z; o[3] = (__bf16)v.w;
  *(bf16x4*)(xcat + (size_t)i * KCAT + t * 4) = o;
}

// ---------------- weights: [Wself;Wneigh] -> W^T bf16 [1024][2048] ----------------
__global__ __launch_bounds__(256) void k_wconv(const float* __restrict__ Ws,
                                               const float* __restrict__ Wn,
                                               __bf16* __restrict__ Wt) {
  __shared__ float tile[32][33];
  int k0 = blockIdx.x * 32;
  int c0 = blockIdx.y * 32;
  for (int i = threadIdx.y; i < 32; i += 8) {
    int k = k0 + i, c = c0 + threadIdx.x;
    float v = (k < DD) ? Ws[(size_t)k * DD + c] : Wn[(size_t)(k - DD) * DD + c];
    tile[i][threadIdx.x] = v;
  }
  __syncthreads();
  for (int i = threadIdx.y; i < 32; i += 8) {
    int c = c0 + i, k = k0 + threadIdx.x;
    Wt[(size_t)c * KCAT + k] = (__bf16)tile[threadIdx.x][i];
  }
}

// ---------------- mean aggregation: wave-per-node, 32B/lane, 2 streams ----------------
__global__ __launch_bounds__(256) void k_agg(__bf16* __restrict__ buf,
                                             const int* __restrict__ off,
                                             const int* __restrict__ eidx) {
  int wid = blockIdx.x * 4 + (threadIdx.x >> 6);   // node id
  if (wid >= N_NODES) return;
  int lane = threadIdx.x & 63;
  int s = off[wid], e = off[wid + 1];
  size_t col = (size_t)lane * 16;                  // 16 bf16 = 32B per lane
  float acc0[16], acc1[16];
#pragma unroll
  for (int j = 0; j < 16; ++j) { acc0[j] = 0.f; acc1[j] = 0.f; }
  int i = s;
  for (; i + 2 <= e; i += 2) {
    const __bf16* r0 = buf + (size_t)eidx[i] * KCAT + col;
    const __bf16* r1 = buf + (size_t)eidx[i + 1] * KCAT + col;
    bf16x8 u0 = *(const bf16x8*)r0;
    bf16x8 u1 = *(const bf16x8*)(r0 + 8);
    bf16x8 v0 = *(const bf16x8*)r1;
    bf16x8 v1 = *(const bf16x8*)(r1 + 8);
#pragma unroll
    for (int j = 0; j < 8; ++j) {
      acc0[j]     += (float)u0[j];
      acc0[8 + j] += (float)u1[j];
      acc1[j]     += (float)v0[j];
      acc1[8 + j] += (float)v1[j];
    }
  }
  if (i < e) {
    const __bf16* r0 = buf + (size_t)eidx[i] * KCAT + col;
    bf16x8 u0 = *(const bf16x8*)r0;
    bf16x8 u1 = *(const bf16x8*)(r0 + 8);
#pragma unroll
    for (int j = 0; j < 8; ++j) { acc0[j] += (float)u0[j]; acc0[8 + j] += (float)u1[j]; }
  }
  float inv = 1.0f / fmaxf((float)(e - s), 1.0f);
  bf16x8 o0, o1;
#pragma unroll
  for (int j = 0; j < 8; ++j) {
    o0[j] = (__bf16)((acc0[j] + acc1[j]) * inv);
    o1[j] = (__bf16)((acc0[8 + j] + acc1[8 + j]) * inv);
  }
  __bf16* dstp = buf + (size_t)wid * KCAT + DD + col;
  *(bf16x8*)dstp = o0;
  *(bf16x8*)(dstp + 8) = o1;
}

// ---------------- GEMM: C[M,1024] = A[M,2048] @ Wt^T + bias ----------------
// 128x128 tile, BK=64, 4 waves (2x2), T3-minimum 2-phase double-buffered LDS:
//   stage(next) -> ds_read(cur)+MFMA -> one syncthreads (drains vmcnt+lgkm) -> swap.
// LDS 64KB (2 x (16KB A | 16KB B)). Pre-swizzled global source + XOR-swizzled
// ds_read (byte ^= (row&7)<<4), linear gload_lds dest (rule #21).
// Block decode: bijective XCD-chunked, N-fastest (632 = 8*79) for A-panel L2 reuse.
template <int MODE>
__global__ __launch_bounds__(256, 2) void k_gemm(const __bf16* __restrict__ A,
                                                 const __bf16* __restrict__ Bt,
                                                 const float* __restrict__ bias,
                                                 float* __restrict__ Cf,
                                                 __bf16* __restrict__ Cb,
                                                 int Mreal) {
  __shared__ char smem[65536];
  const int tid  = threadIdx.x;
  const int lane = tid & 63;
  const int w    = tid >> 6;
  const int wr   = w >> 1, wc = w & 1;
  // HW round-robins consecutive blockIdx.x across the 8 XCDs; this decode gives
  // XCD x the logical tile range [79x, 79x+79) with n fastest -> A-panel L2 reuse.
  const int b  = blockIdx.x;
  const int l  = (b & 7) * MTILES + (b >> 3);
  const int m0 = (l >> 3) * 128;
  const int n0 = (l & 7) * 128;

  f32x4 acc[4][4];
#pragma unroll
  for (int m = 0; m < 4; ++m)
#pragma unroll
    for (int n = 0; n < 4; ++n) acc[m][n] = f32x4{0.f, 0.f, 0.f, 0.f};

  // staging source coords: granule G = chunk*64+lane, E = G ^ ((G>>3)&7)
  int sr[4], sk[4];
#pragma unroll
  for (int i = 0; i < 4; ++i) {
    int G = (4 * w + i) * 64 + lane;
    int E = G ^ ((G >> 3) & 7);
    sr[i] = E >> 3;
    sk[i] = (E & 7) * 8;
  }

  auto stage = [&](int buf, int kt) {
    char* As = smem + buf * 32768;
    char* Bs = As + 16384;
#pragma unroll
    for (int i = 0; i < 4; ++i) {
      gload_lds16(A + (size_t)(m0 + sr[i]) * KCAT + (kt + sk[i]), As + (4 * w + i) * 1024);
      gload_lds16(Bt + (size_t)(n0 + sr[i]) * KCAT + (kt + sk[i]), Bs + (4 * w + i) * 1024);
    }
  };

  auto compute = [&](int buf) {
    char* As = smem + buf * 32768;
    char* Bs = As + 16384;
#pragma unroll
    for (int kk = 0; kk < 64; kk += 32) {
      const int koff = kk + ((lane >> 4) * 8);
      bf16x8 af[4], bfr[4];
#pragma unroll
      for (int m = 0; m < 4; ++m) {
        int r = wr * 64 + m * 16 + (lane & 15);
        int byte = ((r * 64 + koff) * 2) ^ ((r & 7) << 4);
        af[m] = *(const bf16x8*)(As + byte);
      }
#pragma unroll
      for (int n = 0; n < 4; ++n) {
        int c = wc * 64 + n * 16 + (lane & 15);
        int byte = ((c * 64 + koff) * 2) ^ ((c & 7) << 4);
        bfr[n] = *(const bf16x8*)(Bs + byte);
      }
#pragma unroll
      for (int m = 0; m < 4; ++m)
#pragma unroll
        for (int n = 0; n < 4; ++n)
          acc[m][n] = __builtin_amdgcn_mfma_f32_16x16x32_bf16(af[m], bfr[n], acc[m][n], 0, 0, 0);
    }
  };

  // T3-minimum 2-phase pipeline
  stage(0, 0);
  __syncthreads();               // compiler drains vmcnt(0) before barrier
  int cur = 0;
  for (int kt = 0; kt < KCAT; kt += 64) {
    if (kt + 64 < KCAT) stage(cur ^ 1, kt + 64);  // issue next-tile loads first
    compute(cur);                                  // ds_read + MFMA on current
    __syncthreads();                               // single drain per K-step
    cur ^= 1;
  }

  // epilogue: C/D layout col=lane&15, row=(lane>>4)*4+j (m89-verified)
  const int rb = m0 + wr * 64;
  const int cb = n0 + wc * 64;
#pragma unroll
  for (int m = 0; m < 4; ++m) {
#pragma unroll
    for (int n = 0; n < 4; ++n) {
      int c = cb + n * 16 + (lane & 15);
      float bv = bias[c];
#pragma unroll
      for (int j = 0; j < 4; ++j) {
        int r = rb + m * 16 + (lane >> 4) * 4 + j;
        if (r < Mreal) {
          float v = acc[m][n][j] + bv;
          if constexpr (MODE == 1) {
            v = fmaxf(v, 0.f);
            Cb[(size_t)r * KCAT + c] = (__bf16)v;   // left half of hcat
          } else {
            Cf[(size_t)r * DD + c] = v;
          }
        }
      }
    }
  }
}

// ---------------- launcher ----------------
extern "C" void kernel_launch(void* const* d_in, const int* in_sizes, int n_in,
                              void* d_out, int out_size, void* d_ws, size_t ws_size,
                              hipStream_t stream) {
  const int*   node = (const int*)d_in[0];
  const int*   srcv = (const int*)d_in[1];
  const int*   dstv = (const int*)d_in[2];
  const float* emb  = (const float*)d_in[3];
  const float* W1s  = (const float*)d_in[4];
  const float* W1n  = (const float*)d_in[5];
  const float* b1   = (const float*)d_in[6];
  const float* W2s  = (const float*)d_in[7];
  const float* W2n  = (const float*)d_in[8];
  const float* b2   = (const float*)d_in[9];
  float* out = (float*)d_out;

  char* ws = (char*)d_ws;
  __bf16* xcat = (__bf16*)ws; ws += (size_t)MPAD * KCAT * 2;   // 41.9 MB  [x | hneigh1]
  __bf16* hcat = (__bf16*)ws; ws += (size_t)MPAD * KCAT * 2;   // 41.9 MB  [h1 | hneigh2]
  __bf16* Wt1  = (__bf16*)ws; ws += (size_t)DD * KCAT * 2;     // 4.2 MB
  __bf16* Wt2  = (__bf16*)ws; ws += (size_t)DD * KCAT * 2;     // 4.2 MB
  int* deg    = (int*)ws; ws += 40960;
  int* cursor = (int*)ws; ws += 40960;
  int* off    = (int*)ws; ws += 40960;
  int* eidx   = (int*)ws; ws += (size_t)N_EDGES * 4;

  hipMemsetAsync(deg, 0, N_NODES * sizeof(int), stream);
  hipMemsetAsync(cursor, 0, N_NODES * sizeof(int), stream);

  // CSR by dst
  k_hist<<<(N_EDGES + 255) / 256, 256, 0, stream>>>(dstv, deg);
  k_scan<<<1, 1024, 0, stream>>>(deg, off);
  k_fill<<<(N_EDGES + 255) / 256, 256, 0, stream>>>(srcv, dstv, off, cursor, eidx);

  // inputs -> bf16
  k_embed<<<N_NODES, 256, 0, stream>>>(node, emb, xcat);
  k_wconv<<<dim3(64, 32), dim3(32, 8), 0, stream>>>(W1s, W1n, Wt1);
  k_wconv<<<dim3(64, 32), dim3(32, 8), 0, stream>>>(W2s, W2n, Wt2);

  // layer 1
  k_agg<<<2500, 256, 0, stream>>>(xcat, off, eidx);
  k_gemm<1><<<NBLK, 256, 0, stream>>>(xcat, Wt1, b1, nullptr, hcat, N_NODES);

  // layer 2
  k_agg<<<2500, 256, 0, stream>>>(hcat, off, eidx);
  k_gemm<0><<<NBLK, 256, 0, stream>>>(hcat, Wt2, b2, out, nullptr, N_NODES);
}